// Round 11
// baseline (197.849 us; speedup 1.0000x reference)
//
#include <hip/hip_runtime.h>
#include <stdint.h>

#define NS 10
#define DIM 512
#define NQ 4096
#define NP 1024

typedef unsigned short ushort_t;
typedef __bf16 bf16el_t;
typedef bf16el_t bf16x8 __attribute__((ext_vector_type(8)));
typedef float floatx4 __attribute__((ext_vector_type(4)));

// ================= threefry2x32-20 (JAX-compatible, partitionable path) =================
__host__ __device__ __forceinline__ uint32_t rotl32(uint32_t x, int r) {
  return (x << r) | (x >> (32 - r));
}

__host__ __device__ __forceinline__ void threefry2x32(uint32_t k0, uint32_t k1,
                                                      uint32_t x0, uint32_t x1,
                                                      uint32_t* o0, uint32_t* o1) {
  uint32_t ks2 = k0 ^ k1 ^ 0x1BD11BDAu;
  x0 += k0; x1 += k1;
#define TF_R(r) { x0 += x1; x1 = rotl32(x1, r); x1 ^= x0; }
  TF_R(13) TF_R(15) TF_R(26) TF_R(6)   x0 += k1;  x1 += ks2 + 1u;
  TF_R(17) TF_R(29) TF_R(16) TF_R(24)  x0 += ks2; x1 += k0 + 2u;
  TF_R(13) TF_R(15) TF_R(26) TF_R(6)   x0 += k0;  x1 += k1 + 3u;
  TF_R(17) TF_R(29) TF_R(16) TF_R(24)  x0 += k1;  x1 += ks2 + 4u;
  TF_R(13) TF_R(15) TF_R(26) TF_R(6)   x0 += ks2; x1 += k0 + 5u;
#undef TF_R
  *o0 = x0; *o1 = x1;
}

__device__ __forceinline__ uint32_t jax_random_bits(uint32_t k0, uint32_t k1, uint32_t idx) {
  uint32_t o0, o1;
  threefry2x32(k0, k1, 0u, idx, &o0, &o1);
  return o0 ^ o1;
}

// XLA ErfInv32 (Giles polynomial)
__device__ __forceinline__ float erfinvf_xla(float x) {
  float w = -log1pf(-x * x);
  float p;
  if (w < 5.0f) {
    w -= 2.5f;
    p = 2.81022636e-08f;
    p = fmaf(p, w, 3.43273939e-07f);
    p = fmaf(p, w, -3.5233877e-06f);
    p = fmaf(p, w, -4.39150654e-06f);
    p = fmaf(p, w, 0.00021858087f);
    p = fmaf(p, w, -0.00125372503f);
    p = fmaf(p, w, -0.00417768164f);
    p = fmaf(p, w, 0.246640727f);
    p = fmaf(p, w, 1.50140941f);
  } else {
    w = sqrtf(w) - 3.0f;
    p = -0.000200214257f;
    p = fmaf(p, w, 0.000100950558f);
    p = fmaf(p, w, 0.00134934322f);
    p = fmaf(p, w, -0.00367342844f);
    p = fmaf(p, w, 0.00573950773f);
    p = fmaf(p, w, -0.0076224613f);
    p = fmaf(p, w, 0.00943887047f);
    p = fmaf(p, w, 1.00167406f);
    p = fmaf(p, w, 2.83297682f);
  }
  return p * x;
}

__device__ __forceinline__ float jax_bits_to_normal(uint32_t bits) {
  float f = __uint_as_float((bits >> 9) | 0x3F800000u) - 1.0f;
  float u = f * 2.0f - 0.99999994f;
  u = fmaxf(u, -0.99999994f);
  return 1.41421356f * erfinvf_xla(u);
}

__device__ __forceinline__ float softplusf(float x) { return log1pf(expf(x)); }

__device__ __forceinline__ float bf2f(ushort_t u) {
  return __uint_as_float(((uint32_t)u) << 16);
}
__device__ __forceinline__ ushort_t f2bf(float f) {
  uint32_t u = __float_as_uint(f);
  u += 0x7FFFu + ((u >> 16) & 1u);
  return (ushort_t)(u >> 16);
}

// async global->LDS, 16B per lane. LDS dst = wave-uniform base + lane*16.
__device__ __forceinline__ void gll16(const void* g, void* l) {
  __builtin_amdgcn_global_load_lds(
      (const __attribute__((address_space(1))) uint32_t*)g,
      (__attribute__((address_space(3))) uint32_t*)l, 16, 0, 0);
}

// ================= fused prep: gen_w(tiled) | cvt_q | cvt_p+sqp | gen_b | zero sqq =======
__global__ __launch_bounds__(256) void prep_kernel(const float* __restrict__ qf,
                                                   const float* __restrict__ pf,
                                                   const float* __restrict__ wmu,
                                                   const float* __restrict__ wrho,
                                                   const float* __restrict__ bmu,
                                                   const float* __restrict__ brho,
                                                   ushort_t* __restrict__ wt,
                                                   ushort_t* __restrict__ qb,
                                                   ushort_t* __restrict__ pb,
                                                   float* __restrict__ sqp,
                                                   float* __restrict__ bvec,
                                                   float* __restrict__ sqq,
                                                   uint32_t kw0, uint32_t kw1,
                                                   uint32_t kb0, uint32_t kb1) {
  __shared__ __align__(16) ushort_t lsW[64 * 64];   // 8 KB transpose tile
  const int blk = blockIdx.x;
  const int tid = threadIdx.x;
  if (blk < 640) {                       // ---- gen_w: 64x64 tiles, (s, kt, et) ----
    const int s = blk >> 6;
    const int rem = blk & 63;
    const int k0 = (rem >> 3) * 64;
    const int e0 = (rem & 7) * 64;
    const int r = tid >> 2;              // 0..63: local k row
    const int ch = tid & 3;              // 16-float e chunk
    const int kg = k0 + r;
    const int eg = e0 + ch * 16;
    const float* mup = wmu + kg * DIM + eg;
    const float* rhop = wrho + kg * DIM + eg;
    __align__(16) ushort_t wv[16];
#pragma unroll
    for (int v = 0; v < 4; ++v) {
      float4 m4 = *(const float4*)(mup + v * 4);
      float4 r4 = *(const float4*)(rhop + v * 4);
      float ms[4] = {m4.x, m4.y, m4.z, m4.w};
      float rs[4] = {r4.x, r4.y, r4.z, r4.w};
#pragma unroll
      for (int u = 0; u < 4; ++u) {
        uint32_t e = (uint32_t)(eg + v * 4 + u);
        uint32_t eps_idx = ((uint32_t)s << 18) | ((uint32_t)kg << 9) | e;  // JAX [s][k][e]
        float n = jax_bits_to_normal(jax_random_bits(kw0, kw1, eps_idx));
        wv[v * 4 + u] = f2bf(ms[u] + softplusf(rs[u]) * n);
      }
    }
    // swizzled store into [k][e] tile: element (r,e) at r*64 + ((e>>3 ^ (r&7))<<3) + (e&7)
    ushort_t* lrow = lsW + r * 64;
    *(uint4*)&lrow[((2 * ch) ^ (r & 7)) << 3]     = *(const uint4*)&wv[0];
    *(uint4*)&lrow[((2 * ch + 1) ^ (r & 7)) << 3] = *(const uint4*)&wv[8];
    __syncthreads();
    // transpose-read: output row e (64 k's = 128 B); thread -> (er, kc)
    const int er = tid >> 2;
    const int kc = tid & 3;
    __align__(16) ushort_t ov[16];
#pragma unroll
    for (int j = 0; j < 16; ++j) {
      int k = kc * 16 + j;
      ov[j] = lsW[k * 64 + ((((er >> 3) ^ (k & 7)) << 3)) + (er & 7)];
    }
    ushort_t* orow = wt + (size_t)s * (DIM * DIM) + (size_t)(e0 + er) * DIM + k0 + kc * 16;
    *(uint4*)&orow[0] = *(const uint4*)&ov[0];
    *(uint4*)&orow[8] = *(const uint4*)&ov[8];
  } else if (blk < 2688) {               // ---- cvt_q: 2,097,152 floats ----
    int i = ((blk - 640) * 256 + tid) * 4;
    float4 v = *(const float4*)&qf[i];
    uint2 r;
    r.x = (uint32_t)f2bf(v.x) | ((uint32_t)f2bf(v.y) << 16);
    r.y = (uint32_t)f2bf(v.z) | ((uint32_t)f2bf(v.w) << 16);
    *(uint2*)&qb[i] = r;
  } else if (blk < 2944) {               // ---- cvt_p + sqp: 4 protos / block ----
    int p = (blk - 2688) * 4 + (tid >> 6);
    int lane = tid & 63;
    const float* src = pf + p * DIM + lane * 8;
    float4 a = *(const float4*)src;
    float4 b = *(const float4*)(src + 4);
    float vals[8] = {a.x, a.y, a.z, a.w, b.x, b.y, b.z, b.w};
    ushort_t o[8];
    float ss = 0.f;
#pragma unroll
    for (int i = 0; i < 8; ++i) {
      o[i] = f2bf(vals[i]);
      float f = bf2f(o[i]);
      ss += f * f;
    }
    *(uint4*)&pb[p * DIM + lane * 8] = *(const uint4*)o;
#pragma unroll
    for (int off = 32; off; off >>= 1) ss += __shfl_xor(ss, off, 64);
    if (lane == 0) sqp[p] = ss;
  } else if (blk < 2964) {               // ---- gen_b: 5120 ----
    uint32_t t2 = (blk - 2944) * 256u + tid;
    uint32_t e = t2 & 511u;
    uint32_t bits = jax_random_bits(kb0, kb1, t2);
    float n = jax_bits_to_normal(bits);
    bvec[t2] = bmu[e] + softplusf(brho[e]) * n;
  } else {                               // ---- zero sqq: 40960 floats ----
    int i = (blk - 2964) * 256 + tid;
    sqq[i] = 0.f;
  }
}

// ================= GEMM1: tq[s] = q @ W_s + b_s — operand-swapped epilogue ===============
// 128x128 tile, BK=64, global_load_lds + 8-chunk swizzle, 4 waves of 64x64. grid (32,4,10).
// mfma(bF, aF) computes D^T: col=lane&15 -> q, row=(lane>>4)*4+r -> e. Each lane's 4 acc
// regs = 4 consecutive e for fixed q -> direct packed dwordx2 stores, NO LDS transpose,
// NO epilogue barriers. sqq folded via 2 shuffles (jc lanes cover disjoint e) + 1 atomic.
__global__ __launch_bounds__(256) void gemm_tq_kernel(const ushort_t* __restrict__ qb,
                                                      const ushort_t* __restrict__ wt,
                                                      const float* __restrict__ bvec,
                                                      ushort_t* __restrict__ tq,
                                                      float* __restrict__ sqq) {
  __shared__ __align__(16) ushort_t lsA[128 * 64];   // 16 KB
  __shared__ __align__(16) ushort_t lsB[128 * 64];   // 16 KB
  const int lane = threadIdx.x & 63;
  const int wave = threadIdx.x >> 6;
  const int wm = wave >> 1, wn = wave & 1;   // 2x2 wave grid, 64x64 each
  const int qBase = blockIdx.x * 128;
  const int eBase = blockIdx.y * 128;
  const int s = blockIdx.z;
  const ushort_t* wbase = wt + (size_t)s * (DIM * DIM);  // [e][k]
  const int srow = lane >> 3;                       // 0..7
  const int scol = ((lane & 7) ^ srow) * 16;        // swizzled global chunk (bytes)
  const char* gA = (const char*)qb + (size_t)(qBase + wave * 32 + srow) * (DIM * 2) + scol;
  const char* gB = (const char*)wbase + (size_t)(eBase + wave * 32 + srow) * (DIM * 2) + scol;
  char* lA = (char*)&lsA[wave * 32 * 64];
  char* lB = (char*)&lsB[wave * 32 * 64];
  const int cn = lane & 15;
  const int cn7 = cn & 7;
  const int jc = lane >> 4;                         // 0..3
  const floatx4 fzero = {0.f, 0.f, 0.f, 0.f};
  floatx4 acc[4][4];                                // [ei][qi]
#pragma unroll
  for (int ei = 0; ei < 4; ++ei)
#pragma unroll
    for (int qi = 0; qi < 4; ++qi) acc[ei][qi] = fzero;

  for (int kt = 0; kt < 8; ++kt) {
    __syncthreads();
#pragma unroll
    for (int j = 0; j < 4; ++j) {
      gll16(gA + (size_t)j * 8 * (DIM * 2), lA + j * 1024);
      gll16(gB + (size_t)j * 8 * (DIM * 2), lB + j * 1024);
    }
    gA += 128; gB += 128;
    __syncthreads();
#pragma unroll
    for (int c = 0; c < 8; c += 4) {                // logical chunk base (kk = c*8)
      const int po = ((c + jc) ^ cn7) << 3;         // swizzled element offset in row
      bf16x8 aF[4], bF[4];
#pragma unroll
      for (int qi = 0; qi < 4; ++qi)
        aF[qi] = *(const bf16x8*)&lsA[(wm * 64 + qi * 16 + cn) * 64 + po];
#pragma unroll
      for (int ei = 0; ei < 4; ++ei)
        bF[ei] = *(const bf16x8*)&lsB[(wn * 64 + ei * 16 + cn) * 64 + po];
#pragma unroll
      for (int ei = 0; ei < 4; ++ei)
#pragma unroll
        for (int qi = 0; qi < 4; ++qi)
          acc[ei][qi] = __builtin_amdgcn_mfma_f32_16x16x32_bf16(bF[ei], aF[qi], acc[ei][qi], 0, 0, 0);
    }
  }

  // ---- epilogue: direct packed stores (no LDS, no barriers) ----
  const size_t tqs = (size_t)s * (NQ * DIM);
  const int eW = eBase + wn * 64;                   // wave's e window base
  float4 bv4[4];
#pragma unroll
  for (int ei = 0; ei < 4; ++ei)
    bv4[ei] = *(const float4*)&bvec[s * DIM + eW + ei * 16 + jc * 4];
#pragma unroll
  for (int qi = 0; qi < 4; ++qi) {
    const int q = qBase + wm * 64 + qi * 16 + cn;
    ushort_t* rowp = tq + tqs + (size_t)q * DIM + eW + jc * 4;
    float ss = 0.f;
#pragma unroll
    for (int ei = 0; ei < 4; ++ei) {
      float vv[4] = {acc[ei][qi][0] + bv4[ei].x, acc[ei][qi][1] + bv4[ei].y,
                     acc[ei][qi][2] + bv4[ei].z, acc[ei][qi][3] + bv4[ei].w};
      ushort_t us[4];
#pragma unroll
      for (int j = 0; j < 4; ++j) {
        us[j] = f2bf(vv[j]);
        float rv = bf2f(us[j]);                     // rounded value (consistency with cross)
        ss += rv * rv;
      }
      uint2 pk;
      pk.x = (uint32_t)us[0] | ((uint32_t)us[1] << 16);
      pk.y = (uint32_t)us[2] | ((uint32_t)us[3] << 16);
      *(uint2*)&rowp[ei * 16] = pk;
    }
    ss += __shfl_xor(ss, 16, 64);                   // jc lanes cover disjoint e sets
    ss += __shfl_xor(ss, 32, 64);
    if (jc == 0) atomicAdd(&sqq[s * NQ + q], ss);
  }
}

// ================= GEMM2 fused dist/mean/std — 64q x 128p, s-groups {4,4,2} (R10) ========
__global__ __launch_bounds__(256, 2) void gemm_dist_kernel(const ushort_t* __restrict__ tq,
                                                           const ushort_t* __restrict__ pb,
                                                           const float* __restrict__ sqq,
                                                           const float* __restrict__ sqp,
                                                           float* __restrict__ out) {
  __shared__ __align__(16) ushort_t lsA[4 * 64 * 64];   // 32 KB: A(s0..s3), row=128B
  __shared__ __align__(16) ushort_t lsB[128 * 64];      // 16 KB
  const int lane = threadIdx.x & 63;
  const int wave = threadIdx.x >> 6;   // 0..3
  const int wm = wave >> 1;            // q offset 32*wm
  const int wn = wave & 1;             // p offset 64*wn
  const int qBase = blockIdx.x * 64;
  const int pBase = blockIdx.y * 128;
  const int srow = lane >> 3;          // 0..7
  const int scol = ((lane & 7) ^ srow) * 16;   // swizzled global chunk (bytes)
  const int cn = lane & 15;
  const int cn7 = cn & 7;
  const int jc = lane >> 4;
  const int rq = jc * 4;
  const floatx4 fzero = {0.f, 0.f, 0.f, 0.f};
  const char* gAb = (const char*)tq + (size_t)(qBase + wave * 16 + srow) * (DIM * 2) + scol;
  const char* gBb = (const char*)pb + (size_t)(pBase + wave * 32 + srow) * (DIM * 2) + scol;
  char* lAw = (char*)lsA + wave * 2048;          // within each sample's 8 KB quarter
  char* lBw = (char*)lsB + wave * 4096;
  int po[2];
#pragma unroll
  for (int c = 0; c < 2; ++c) po[c] = ((c * 4 + jc) ^ cn7) << 3;

  float sum[2][4][4] = {};   // [mi][ni][r]
  float ssq[2][4][4] = {};
  float sqp_v[4];
#pragma unroll
  for (int ni = 0; ni < 4; ++ni) sqp_v[ni] = sqp[pBase + wn * 64 + ni * 16 + cn];

  for (int grp = 0; grp < 3; ++grp) {
    const int sbase = grp * 4;               // groups: {0..3}, {4..7}, {8..9}
    const int gsz = (grp == 2) ? 2 : 4;
    floatx4 acc[4][2][4];                    // [sp][mi][ni]
#pragma unroll
    for (int sp = 0; sp < 4; ++sp)
#pragma unroll
      for (int mi = 0; mi < 2; ++mi)
#pragma unroll
        for (int ni = 0; ni < 4; ++ni) acc[sp][mi][ni] = fzero;

    const char* gAg = gAb + (size_t)sbase * (NQ * DIM * 2);
    const char* gBk = gBb;
    for (int kt = 0; kt < 8; ++kt) {
      __syncthreads();
#pragma unroll
      for (int sp = 0; sp < 4; ++sp)
        if (sp < gsz) {
          const char* gs = gAg + (size_t)sp * (NQ * DIM * 2);
          char* ls = lAw + sp * 8192;
          gll16(gs, ls);
          gll16(gs + (size_t)8 * (DIM * 2), ls + 1024);
        }
#pragma unroll
      for (int j = 0; j < 4; ++j)
        gll16(gBk + (size_t)j * 8 * (DIM * 2), lBw + j * 1024);
      gAg += 128; gBk += 128;
      __syncthreads();
#pragma unroll
      for (int c = 0; c < 2; ++c) {
        bf16x8 bF[4];
#pragma unroll
        for (int ni = 0; ni < 4; ++ni)
          bF[ni] = *(const bf16x8*)&lsB[(wn * 64 + ni * 16 + cn) * 64 + po[c]];
#pragma unroll
        for (int sp = 0; sp < 4; ++sp)
          if (sp < gsz) {
            bf16x8 aF[2];
#pragma unroll
            for (int mi = 0; mi < 2; ++mi)
              aF[mi] = *(const bf16x8*)&lsA[sp * 4096 + (wm * 32 + mi * 16 + cn) * 64 + po[c]];
#pragma unroll
            for (int mi = 0; mi < 2; ++mi)
#pragma unroll
              for (int ni = 0; ni < 4; ++ni)
                acc[sp][mi][ni] =
                    __builtin_amdgcn_mfma_f32_16x16x32_bf16(aF[mi], bF[ni], acc[sp][mi][ni], 0, 0, 0);
          }
      }
    }
    // fold group samples into running stats (ssq accumulates pre-sqrt sqd)
#pragma unroll
    for (int sp = 0; sp < 4; ++sp)
      if (sp < gsz) {
        const int s = sbase + sp;
#pragma unroll
        for (int mi = 0; mi < 2; ++mi) {
          float4 aqv = *(const float4*)&sqq[s * NQ + qBase + wm * 32 + mi * 16 + rq];
          float aqa[4] = {aqv.x, aqv.y, aqv.z, aqv.w};
#pragma unroll
          for (int r = 0; r < 4; ++r) {
            float aq = aqa[r];
#pragma unroll
            for (int ni = 0; ni < 4; ++ni) {
              float sqd = fmaxf(fmaf(-2.0f, acc[sp][mi][ni][r], aq + sqp_v[ni]), 1e-12f);
              sum[mi][ni][r] += sqrtf(sqd);
              ssq[mi][ni][r] += sqd;
            }
          }
        }
      }
  }
#pragma unroll
  for (int mi = 0; mi < 2; ++mi)
#pragma unroll
    for (int ni = 0; ni < 4; ++ni)
#pragma unroll
      for (int r = 0; r < 4; ++r) {
        int q = qBase + wm * 32 + mi * 16 + rq + r;
        int p = pBase + wn * 64 + ni * 16 + cn;
        float sm = sum[mi][ni][r];
        float mean = sm * 0.1f;
        float var = (ssq[mi][ni][r] - sm * sm * 0.1f) * (1.0f / 9.0f);
        out[(size_t)q * NP + p] = mean;
        out[(size_t)NQ * NP + (size_t)q * NP + p] = sqrtf(fmaxf(var, 0.0f));
      }
}

// ================= launch =================
extern "C" void kernel_launch(void* const* d_in, const int* in_sizes, int n_in,
                              void* d_out, int out_size, void* d_ws, size_t ws_size,
                              hipStream_t stream) {
  const float* qf   = (const float*)d_in[0];
  const float* pf   = (const float*)d_in[1];
  const float* wmu  = (const float*)d_in[2];
  const float* wrho = (const float*)d_in[3];
  const float* bmu  = (const float*)d_in[4];
  const float* brho = (const float*)d_in[5];
  float* out = (float*)d_out;
  char* ws = (char*)d_ws;
  ushort_t* wt   = (ushort_t*)(ws);              //  5,242,880  W^T bf16 [s][e][k]
  ushort_t* qb   = (ushort_t*)(ws + 5242880);    //  4,194,304  query bf16
  ushort_t* pb   = (ushort_t*)(ws + 9437184);    //  1,048,576  proto bf16
  float*    bvec = (float*)   (ws + 10485760);   //     20,480  bias samples
  float*    sqp  = (float*)   (ws + 10506240);   //      4,096  ||p||^2
  ushort_t* tq   = (ushort_t*)(ws + 10510336);   // 41,943,040  tq bf16 [s][q][e]
  float*    sqq  = (float*)   (ws + 52453376);   //    163,840  ||tq||^2 (atomic-accumulated)

  uint32_t kw0, kw1, kb0, kb1;
  threefry2x32(0u, 42u, 0u, 0u, &kw0, &kw1);
  threefry2x32(0u, 42u, 0u, 1u, &kb0, &kb1);

  hipLaunchKernelGGL(prep_kernel, dim3(3124), dim3(256), 0, stream,
                     qf, pf, wmu, wrho, bmu, brho, wt, qb, pb, sqp, bvec, sqq,
                     kw0, kw1, kb0, kb1);
  hipLaunchKernelGGL(gemm_tq_kernel, dim3(32, 4, 10), dim3(256), 0, stream, qb, wt, bvec, tq, sqq);
  hipLaunchKernelGGL(gemm_dist_kernel, dim3(64, 8), dim3(256), 0, stream, tq, pb, sqq, sqp, out);
}